// Round 9
// baseline (435.298 us; speedup 1.0000x reference)
//
#include <hip/hip_runtime.h>

#define B_ 4
#define C_ 512
#define CI_ 256
#define N_ 4096
#define SCALE_PAM 0.04419417382415922f  // 1/sqrt(512)
#define SCALE_CAM (1.0f/64.0f)          // 1/sqrt(4096)
#define SHIFT_PAM 8.0f

typedef float v4f __attribute__((ext_vector_type(4)));
typedef short v8s __attribute__((ext_vector_type(8)));

__device__ __forceinline__ unsigned short f2bf(float f) {
  unsigned int u = __float_as_uint(f);
  u = (u + 0x7FFFu + ((u >> 16) & 1u)) >> 16;
  return (unsigned short)u;
}
__device__ __forceinline__ float bf2f(unsigned short s) {
  return __uint_as_float(((unsigned int)s) << 16);
}
__device__ __forceinline__ v8s ld8(const unsigned short* p) {
  v8s r; *(int4*)&r = *(const int4*)p; return r;
}
__device__ __forceinline__ v4f mfma16(v8s a, v8s b, v4f c) {
  return __builtin_amdgcn_mfma_f32_16x16x32_bf16(a, b, c, 0, 0, 0);
}
// PK layout: off(r,k) = ((r>>4)*(K>>5) + (k>>5))*512 + (r&15)*32 + (k&31)  [shorts]
// Wave frag load: base + lanelin, lanelin=(lane&15)*32+(lane>>4)*8 -> contiguous 1KB.

// ---------------------------------------------------------------------------
// K_wb: wq/wk/wv fp32 -> w_pk PK(1024,512).
// ---------------------------------------------------------------------------
__global__ __launch_bounds__(256) void k_wb(const float* __restrict__ wq,
                                            const float* __restrict__ wk,
                                            const float* __restrict__ wv,
                                            unsigned short* __restrict__ w_pk) {
  int u = blockIdx.x * 256 + threadIdx.x;
  int blk = u >> 6, wi = (u & 63) * 8;
  int r = (blk >> 4) * 16 + (wi >> 5);
  int k = (blk & 15) * 32 + (wi & 31);
  const float* src = (r < 256) ? &wq[r * 512 + k]
                   : (r < 512) ? &wk[(r - 256) * 512 + k]
                               : &wv[(r - 512) * 512 + k];
  float4 f0 = *(const float4*)src, f1 = *(const float4*)(src + 4);
  ushort4 o0 = { f2bf(f0.x), f2bf(f0.y), f2bf(f0.z), f2bf(f0.w) };
  ushort4 o1 = { f2bf(f1.x), f2bf(f1.y), f2bf(f1.z), f2bf(f1.w) };
  *(ushort4*)&w_pk[u * 8] = o0;
  *(ushort4*)&w_pk[u * 8 + 4] = o1;
}

// ---------------------------------------------------------------------------
// K_xT: x fp32 [b][c][n] -> x_pk PK(4096,512) per batch (rows n, cols c).
// ---------------------------------------------------------------------------
__global__ __launch_bounds__(256) void k_xT(const float* __restrict__ x,
                                            unsigned short* __restrict__ x_pk) {
  const int b = blockIdx.z, c0 = blockIdx.y * 64, n0 = blockIdx.x * 64;
  const int t = threadIdx.x;
  __shared__ unsigned short ts[64 * 72];  // [n][c]
  const int cl = t >> 2, nseg = (t & 3) * 16;
  const float* xr = x + ((size_t)b * C_ + c0 + cl) * N_ + n0 + nseg;
#pragma unroll
  for (int k = 0; k < 4; ++k) {
    float4 f = *(const float4*)(xr + k * 4);
    ts[(nseg + k * 4 + 0) * 72 + cl] = f2bf(f.x);
    ts[(nseg + k * 4 + 1) * 72 + cl] = f2bf(f.y);
    ts[(nseg + k * 4 + 2) * 72 + cl] = f2bf(f.z);
    ts[(nseg + k * 4 + 3) * 72 + cl] = f2bf(f.w);
  }
  __syncthreads();
  unsigned short* dst = x_pk + (size_t)b * N_ * C_;
#pragma unroll
  for (int u = t; u < 512; u += 256) {
    int blk = u >> 6, wi = (u & 63) * 8;
    int rl = (blk >> 1) * 16 + (wi >> 5);
    int kl = (blk & 1) * 32 + (wi & 31);
    int gr = n0 + rl, gk = c0 + kl;
    size_t go = ((size_t)(gr >> 4) * 16 + (gk >> 5)) * 512 + (gr & 15) * 32 + (gk & 31);
    *(int4*)&dst[go] = *(int4*)&ts[rl * 72 + kl];
  }
}

// ---------------------------------------------------------------------------
// K_qkv: y[o][n] = sum_c W[o][c] x[n][c] + b.  128o x 128n tile, 512 thr.
// ---------------------------------------------------------------------------
__global__ __launch_bounds__(512) void k_qkv(
    const unsigned short* __restrict__ w_pk, const unsigned short* __restrict__ x_pk,
    const float* __restrict__ bq, const float* __restrict__ bk, const float* __restrict__ bv,
    unsigned short* __restrict__ q_pk, unsigned short* __restrict__ k_pk,
    unsigned short* __restrict__ v_pk) {
  const int b = blockIdx.z, o0 = blockIdx.y * 128, n0 = blockIdx.x * 128;
  const int t = threadIdx.x, wave = t >> 6, lane = t & 63;
  const int la = lane & 15, quad = lane >> 4;
  const int ow = wave & 1, nw = wave >> 1;
  const int lanelin = la * 32 + quad * 8;
  const unsigned short* xpb = x_pk + (size_t)b * N_ * C_;
  __shared__ unsigned short tp[128 * 136];

  v4f acc[4][2];
#pragma unroll
  for (int i = 0; i < 4; ++i)
#pragma unroll
    for (int j = 0; j < 2; ++j) acc[i][j] = (v4f){0.f, 0.f, 0.f, 0.f};

  const int ar16 = (o0 + ow * 64) >> 4;
  const int br16 = (n0 + nw * 32) >> 4;
#pragma unroll 4
  for (int s = 0; s < 16; ++s) {
    v8s b0 = ld8(&xpb[((size_t)(br16 + 0) * 16 + s) * 512 + lanelin]);
    v8s b1 = ld8(&xpb[((size_t)(br16 + 1) * 16 + s) * 512 + lanelin]);
#pragma unroll
    for (int oi = 0; oi < 4; ++oi) {
      v8s a = ld8(&w_pk[((size_t)(ar16 + oi) * 16 + s) * 512 + lanelin]);
      acc[oi][0] = mfma16(a, b0, acc[oi][0]);
      acc[oi][1] = mfma16(a, b1, acc[oi][1]);
    }
  }

  if (o0 >= 512) {
#pragma unroll
    for (int oi = 0; oi < 4; ++oi)
#pragma unroll
      for (int nj = 0; nj < 2; ++nj)
#pragma unroll
        for (int r = 0; r < 4; ++r) {
          int cl = ow * 64 + oi * 16 + quad * 4 + r;
          int nl = nw * 32 + nj * 16 + la;
          tp[cl * 136 + nl] = f2bf(acc[oi][nj][r] + bv[o0 - 512 + cl]);
        }
    __syncthreads();
    unsigned short* dst = v_pk + (size_t)b * C_ * N_;
#pragma unroll
    for (int u = t; u < 2048; u += 512) {
      int blk = u >> 6, wi = (u & 63) * 8;
      int rl = (blk >> 2) * 16 + (wi >> 5);
      int kl = (blk & 3) * 32 + (wi & 31);
      int gr = (o0 - 512) + rl, gk = n0 + kl;
      size_t go = ((size_t)(gr >> 4) * 128 + (gk >> 5)) * 512 + (gr & 15) * 32 + (gk & 31);
      *(int4*)&dst[go] = *(int4*)&tp[rl * 136 + kl];
    }
  } else {
    const float* bias = (o0 < 256) ? bq : bk;
#pragma unroll
    for (int oi = 0; oi < 4; ++oi)
#pragma unroll
      for (int nj = 0; nj < 2; ++nj)
#pragma unroll
        for (int r = 0; r < 4; ++r) {
          int ol = ow * 64 + oi * 16 + quad * 4 + r;
          int nl = nw * 32 + nj * 16 + la;
          tp[nl * 136 + ol] = f2bf(acc[oi][nj][r] + bias[(o0 & 255) + ol]);
        }
    __syncthreads();
    unsigned short* dst = ((o0 < 256) ? q_pk : k_pk) + (size_t)b * N_ * CI_;
#pragma unroll
    for (int u = t; u < 2048; u += 512) {
      int blk = u >> 6, wi = (u & 63) * 8;
      int rl = (blk >> 2) * 16 + (wi >> 5);
      int kl = (blk & 3) * 32 + (wi & 31);
      int gr = n0 + rl, gk = (o0 & 255) + kl;
      size_t go = ((size_t)(gr >> 4) * 8 + (gk >> 5)) * 512 + (gr & 15) * 32 + (gk & 31);
      *(int4*)&dst[go] = *(int4*)&tp[rl * 136 + kl];
    }
  }
}

// ---------------------------------------------------------------------------
// K_pam v14: producer/consumer wave specialization. 512 thr = 8 waves:
// waves 0-3 PRODUCE (S=QK^T from K-LDS, exp, P->pa), waves 4-7 CONSUME
// (PV from pa + V regs). Each SIMD hosts 1 producer + 1 consumer in
// anti-phase: S(i+1) runs concurrently with PV(i) -> VALU/LDS overlap MFMA
// (v8/v13 post-mortem: lockstep phases serialize the pipes; step ~= sum).
// Register union: v4f u[32] = producers' Q frags (u[0..15], bit_cast) /
// consumers' acc (u[0..31]); loop-carried state fits the 256-reg budget at
// 2 waves/SIMD (__launch_bounds__(512,2)). vf is transient-per-iteration,
// so plain __syncthreads() per iteration suffices (DMA for tile i+2 has a
// full iteration to land; nothing needs to stay in flight across barrier).
// Ping-pong: pa write (i+1)&1 / read i&1; kls write i&1 / read (i+1)&1.
// ---------------------------------------------------------------------------
__device__ __forceinline__ void kstage512(const unsigned short* g, unsigned short* l, int t) {
  // 512 threads stage a contiguous 32KB K tile: 4 x 16B per thread.
#pragma unroll
  for (int u = 0; u < 4; ++u)
    __builtin_amdgcn_global_load_lds(
        (const __attribute__((address_space(1))) void*)(g + (size_t)(u * 512 + t) * 8),
        (__attribute__((address_space(3))) void*)(l + (u * 512 + t) * 8), 16, 0, 0);
}

__device__ __forceinline__ void s_phase(const unsigned short* kslot, unsigned short* patile,
                                        const v4f (&u)[32], float (&lsum)[2][4],
                                        int iw, int jw, int la, int quad, int lanelin) {
#pragma unroll
  for (int js2 = 0; js2 < 2; ++js2) {
    const unsigned short* kb = kslot + (jw * 2 + js2) * 4096 + lanelin;
    v8s kfb[8];
#pragma unroll
    for (int s = 0; s < 8; ++s) kfb[s] = ld8(kb + s * 512);
#pragma unroll
    for (int is2 = 0; is2 < 2; ++is2) {
      v4f sA = (v4f){0.f, 0.f, 0.f, 0.f}, sB = sA;
#pragma unroll
      for (int sh = 0; sh < 4; ++sh) {
        sA = mfma16(__builtin_bit_cast(v8s, u[is2 * 8 + sh]), kfb[sh], sA);
        sB = mfma16(__builtin_bit_cast(v8s, u[is2 * 8 + 4 + sh]), kfb[4 + sh], sB);
      }
#pragma unroll
      for (int r = 0; r < 4; ++r) {
        float p = __expf((sA[r] + sB[r]) * SCALE_PAM - SHIFT_PAM);
        lsum[is2][r] += p;
        int row = iw * 32 + is2 * 16 + quad * 4 + r;
        patile[((row << 6) + (jw * 2 + js2) * 16 + la) ^ ((row & 7) << 3)] = f2bf(p);
      }
    }
  }
}

__global__ __launch_bounds__(512, 2) void k_pam(
    const unsigned short* __restrict__ q_pk, const unsigned short* __restrict__ k_pk,
    const unsigned short* __restrict__ v_pk,
    float* __restrict__ acc_part, float* __restrict__ l_part) {
  const int blk = blockIdx.x;
  const int b = (blk & 7) >> 1, jh = blk & 1, i0 = (blk >> 3) * 64;
  const int t = threadIdx.x, wave = t >> 6, lane = t & 63;
  const int la = lane & 15, quad = lane >> 4;
  const bool prod = wave < 4;
  const int iw = wave & 1, jw = (wave >> 1) & 1;  // producer: 2x32i, 2x32j
  const int cw = wave - 4, cb = cw * 128;         // consumer: 128 ch/wave
  const int lanelin = la * 32 + quad * 8;

  __shared__ unsigned short kls[2][16384];  // 2 x 32KB K tiles (PK chunk copy)
  __shared__ unsigned short pa[2][4096];    // 64x64 P, XOR-swizzled stride 64
  __shared__ float l_lds[64];
  if (t < 64) l_lds[t] = 0.f;

  const unsigned short* qpk = q_pk + (size_t)b * N_ * CI_;
  const unsigned short* kpk = k_pk + (size_t)b * N_ * CI_;
  const unsigned short* vpk = v_pk + (size_t)b * C_ * N_;

  v4f u[32];        // union: producer Q frags u[0..15] / consumer acc u[0..31]
  float lsum[2][4];

  const int jbeg = jh * 2048;

  // prologue: stage tiles 0,1; load Q (producers) / zero acc (consumers)
  kstage512(kpk + (size_t)(jbeg >> 4) * 4096, kls[0], t);
  kstage512(kpk + (size_t)((jbeg + 64) >> 4) * 4096, kls[1], t);
  if (prod) {
#pragma unroll
    for (int rb = 0; rb < 2; ++rb) {
      const unsigned short* qb = qpk + ((size_t)((i0 >> 4) + iw * 2 + rb) * 8) * 512 + lanelin;
#pragma unroll
      for (int s = 0; s < 8; ++s) u[rb * 8 + s] = __builtin_bit_cast(v4f, ld8(qb + s * 512));
    }
#pragma unroll
    for (int is2 = 0; is2 < 2; ++is2)
#pragma unroll
      for (int r = 0; r < 4; ++r) lsum[is2][r] = 0.f;
  } else {
#pragma unroll
    for (int z = 0; z < 32; ++z) u[z] = (v4f){0.f, 0.f, 0.f, 0.f};
  }
  __syncthreads();  // tiles 0,1 staged (vmcnt0); l_lds zeroed

  // producers: S(0) -> pa[0]
  if (prod) s_phase(kls[0], pa[0], u, lsum, iw, jw, la, quad, lanelin);
  __syncthreads();  // P(0) visible

  for (int i = 0; i < 32; ++i) {
    // stage tile i+2 into kls[i&1] (drained by this iteration's barrier)
    if (i < 30)
      kstage512(kpk + (size_t)((jbeg + (i + 2) * 64) >> 4) * 4096, kls[i & 1], t);
    if (prod) {
      if (i < 31) s_phase(kls[(i + 1) & 1], pa[(i + 1) & 1], u, lsum, iw, jw, la, quad, lanelin);
    } else {
      const int j0 = jbeg + i * 64;
      v8s vf[8][2];
#pragma unroll
      for (int ct = 0; ct < 8; ++ct)
#pragma unroll
        for (int ks = 0; ks < 2; ++ks)
          vf[ct][ks] = ld8(&vpk[((size_t)((cb >> 4) + ct) * 128 + (j0 >> 5) + ks) * 512 + lanelin]);
      __builtin_amdgcn_s_setprio(1);
#pragma unroll
      for (int it = 0; it < 4; ++it) {
        const int row = it * 16 + la;
        const int sw = (row & 7) << 3;
#pragma unroll
        for (int ks = 0; ks < 2; ++ks) {
          v8s pf; *(int4*)&pf = *(const int4*)&pa[i & 1][((row << 6) + ks * 32 + quad * 8) ^ sw];
#pragma unroll
          for (int ct = 0; ct < 8; ++ct)
            u[ct * 4 + it] = mfma16(vf[ct][ks], pf, u[ct * 4 + it]);
        }
      }
      __builtin_amdgcn_s_setprio(0);
    }
    __syncthreads();
  }

  // epilogue: l reduction (producers), acc write (consumers)
  if (prod) {
#pragma unroll
    for (int is2 = 0; is2 < 2; ++is2)
#pragma unroll
      for (int r = 0; r < 4; ++r) {
        float v = lsum[is2][r];
        v += __shfl_xor(v, 1); v += __shfl_xor(v, 2);
        v += __shfl_xor(v, 4); v += __shfl_xor(v, 8);
        if (la == 0) atomicAdd(&l_lds[iw * 32 + is2 * 16 + quad * 4 + r], v);
      }
  }
  __syncthreads();
  if (t < 64) l_part[((size_t)jh * B_ + b) * N_ + i0 + t] = l_lds[t];
  if (!prod) {
    float* ap = acc_part + ((size_t)jh * B_ + b) * C_ * N_;
#pragma unroll
    for (int ct = 0; ct < 8; ++ct)
#pragma unroll
      for (int it = 0; it < 4; ++it)
#pragma unroll
        for (int r = 0; r < 4; ++r)
          ap[(size_t)(cb + ct * 16 + quad * 4 + r) * N_ + i0 + it * 16 + la] = u[ct * 4 + it][r];
  }
}

// ---------------------------------------------------------------------------
// K_combine: sa = tanh(gp*(a0+a1)/((l0+l1)*N) + x); emit sa_pk + saT_pk.
// ---------------------------------------------------------------------------
__global__ __launch_bounds__(256) void k_combine(
    const float* __restrict__ acc_part, const float* __restrict__ l_part,
    const float* __restrict__ x, const float* __restrict__ gamma_pam,
    unsigned short* __restrict__ sa_pk, unsigned short* __restrict__ saT_pk) {
  const int b = blockIdx.z, c0 = blockIdx.y * 64, n0 = blockIdx.x * 64;
  const int t = threadIdx.x;
  const int cl = t >> 2, nseg = (t & 3) * 16;
  __shared__ unsigned short ts[64 * 72];
  const float gpv = gamma_pam[0];
  const size_t rowoff = ((size_t)b * C_ + c0 + cl) * N_ + n0 + nseg;
  const float* a0 = acc_part + rowoff;
  const float* a1 = acc_part + (size_t)B_ * C_ * N_ + rowoff;
  const float* xr = x + rowoff;
  const float* l0 = l_part + (size_t)b * N_ + n0 + nseg;
  const float* l1 = l_part + ((size_t)B_ + b) * N_ + n0 + nseg;
  unsigned short sv[16];
#pragma unroll
  for (int k = 0; k < 4; ++k) {
    float4 p4 = *(const float4*)(a0 + k * 4);
    float4 q4 = *(const float4*)(a1 + k * 4);
    float4 x4 = *(const float4*)(xr + k * 4);
    float4 u4 = *(const float4*)(l0 + k * 4);
    float4 w4 = *(const float4*)(l1 + k * 4);
    sv[k * 4 + 0] = f2bf(tanhf(fmaf(gpv, (p4.x + q4.x) / ((u4.x + w4.x) * (float)N_), x4.x)));
    sv[k * 4 + 1] = f2bf(tanhf(fmaf(gpv, (p4.y + q4.y) / ((u4.y + w4.y) * (float)N_), x4.y)));
    sv[k * 4 + 2] = f2bf(tanhf(fmaf(gpv, (p4.z + q4.z) / ((u4.z + w4.z) * (float)N_), x4.z)));
    sv[k * 4 + 3] = f2bf(tanhf(fmaf(gpv, (p4.w + q4.w) / ((u4.w + w4.w) * (float)N_), x4.w)));
  }
  // stage [c][n] -> sa_pk
#pragma unroll
  for (int k = 0; k < 16; ++k) ts[cl * 72 + nseg + k] = sv[k];
  __syncthreads();
  {
    unsigned short* dst = sa_pk + (size_t)b * C_ * N_;
#pragma unroll
    for (int u = t; u < 512; u += 256) {
      int blk = u >> 6, wi = (u & 63) * 8;
      int rl = (blk >> 1) * 16 + (wi >> 5);
      int kl = (blk & 1) * 32 + (wi & 31);
      int gr = c0 + rl, gk = n0 + kl;
      size_t go = ((size_t)(gr >> 4) * 128 + (gk >> 5)) * 512 + (gr & 15) * 32 + (gk & 31);
      *(int4*)&dst[go] = *(int4*)&ts[rl * 72 + kl];
    }
  }
  __syncthreads();
  // stage [n][c] -> saT_pk
#pragma unroll
  for (int k = 0; k < 16; ++k) ts[(nseg + k) * 72 + cl] = sv[k];
  __syncthreads();
  {
    unsigned short* dst = saT_pk + (size_t)b * N_ * C_;
#pragma unroll
    for (int u = t; u < 512; u += 256) {
      int blk = u >> 6, wi = (u & 63) * 8;
      int rl = (blk >> 1) * 16 + (wi >> 5);
      int kl = (blk & 1) * 32 + (wi & 31);
      int gr = n0 + rl, gk = c0 + kl;
      size_t go = ((size_t)(gr >> 4) * 16 + (gk >> 5)) * 512 + (gr & 15) * 32 + (gk & 31);
      *(int4*)&dst[go] = *(int4*)&ts[rl * 72 + kl];
    }
  }
}

// ---------------------------------------------------------------------------
// K_cam_e: e_part[ks][b][c][d] = scale * sum_n sa_c sa_d.  64x64 tile, ks4.
// ---------------------------------------------------------------------------
__global__ __launch_bounds__(256) void k_cam_e(const unsigned short* __restrict__ sa_pk,
                                               float* __restrict__ e_part) {
  const int b = blockIdx.z, ks = blockIdx.y;
  const int c0 = (blockIdx.x & 7) * 64, d0 = (blockIdx.x >> 3) * 64;
  const int t = threadIdx.x, wave = t >> 6, lane = t & 63;
  const int la = lane & 15, quad = lane >> 4;
  const int cw = wave & 1, dw = wave >> 1;
  const int lanelin = la * 32 + quad * 8;
  const unsigned short* sb = sa_pk + (size_t)b * C_ * N_;

  v4f acc[2][2];
#pragma unroll
  for (int i = 0; i < 2; ++i)
#pragma unroll
    for (int j = 0; j < 2; ++j) acc[i][j] = (v4f){0.f, 0.f, 0.f, 0.f};

  const int ar16 = (c0 + cw * 32) >> 4;
  const int br16 = (d0 + dw * 32) >> 4;
#pragma unroll 4
  for (int s = 0; s < 32; ++s) {
    const int k32 = ks * 32 + s;
    v8s a0 = ld8(&sb[((size_t)(ar16 + 0) * 128 + k32) * 512 + lanelin]);
    v8s a1 = ld8(&sb[((size_t)(ar16 + 1) * 128 + k32) * 512 + lanelin]);
    v8s b0 = ld8(&sb[((size_t)(br16 + 0) * 128 + k32) * 512 + lanelin]);
    v8s b1 = ld8(&sb[((size_t)(br16 + 1) * 128 + k32) * 512 + lanelin]);
    acc[0][0] = mfma16(a0, b0, acc[0][0]);
    acc[0][1] = mfma16(a0, b1, acc[0][1]);
    acc[1][0] = mfma16(a1, b0, acc[1][0]);
    acc[1][1] = mfma16(a1, b1, acc[1][1]);
  }
  float* ep = e_part + ((size_t)(ks * B_ + b)) * C_ * C_;
#pragma unroll
  for (int i = 0; i < 2; ++i)
#pragma unroll
    for (int j = 0; j < 2; ++j)
#pragma unroll
      for (int r = 0; r < 4; ++r) {
        int c = c0 + cw * 32 + i * 16 + quad * 4 + r;
        int d = d0 + dw * 32 + j * 16 + la;
        ep[(size_t)c * C_ + d] = acc[i][j][r] * SCALE_CAM;
      }
}

// ---------------------------------------------------------------------------
// K_cam_softmax: min-trick softmax over 4 parts -> attn_pk PK(512,512).
// ---------------------------------------------------------------------------
__global__ __launch_bounds__(64) void k_cam_softmax(const float* __restrict__ e_part,
                                                    unsigned short* __restrict__ attn_pk) {
  const int c = blockIdx.x, b = blockIdx.y, lane = threadIdx.x;
  size_t roff = ((size_t)b * C_ + c) * C_;
  float vals[8];
#pragma unroll
  for (int r = 0; r < 8; ++r) {
    int d = lane + r * 64;
    float s = 0.f;
#pragma unroll
    for (int p = 0; p < 4; ++p) s += e_part[(size_t)(p * B_) * C_ * C_ + roff + d];
    vals[r] = s;
  }
  float mn = vals[0];
#pragma unroll
  for (int r = 1; r < 8; ++r) mn = fminf(mn, vals[r]);
#pragma unroll
  for (int m = 32; m >= 1; m >>= 1) mn = fminf(mn, __shfl_xor(mn, m));
  float sum = 0.f;
#pragma unroll
  for (int r = 0; r < 8; ++r) { vals[r] = __expf(mn - vals[r]); sum += vals[r]; }
#pragma unroll
  for (int m = 32; m >= 1; m >>= 1) sum += __shfl_xor(sum, m);
  float sc = (1.0f / (float)C_) / sum;
  unsigned short* ab = attn_pk + (size_t)b * C_ * C_;
#pragma unroll
  for (int r = 0; r < 8; ++r) {
    int d = lane + r * 64;
    size_t go = ((size_t)(c >> 4) * 16 + (d >> 5)) * 512 + (c & 15) * 32 + (d & 31);
    ab[go] = f2bf(vals[r] * sc);
  }
}

// ---------------------------------------------------------------------------
// K_cam_out: out = gc * (attn @ sa) + sa.  128c x 128n tile, 512 thr.
// ---------------------------------------------------------------------------
__global__ __launch_bounds__(512) void k_cam_out(
    const unsigned short* __restrict__ attn_pk, const unsigned short* __restrict__ saT_pk,
    const unsigned short* __restrict__ sa_pk, const float* __restrict__ gamma_cam,
    float* __restrict__ out) {
  const int b = blockIdx.z, c0 = blockIdx.y * 128, n0 = blockIdx.x * 128;
  const int t = threadIdx.x, wave = t >> 6, lane = t & 63;
  const int la = lane & 15, quad = lane >> 4;
  const int cw = wave & 1, nw = wave >> 1;
  const int lanelin = la * 32 + quad * 8;
  const unsigned short* ab = attn_pk + (size_t)b * C_ * C_;
  const unsigned short* sTb = saT_pk + (size_t)b * N_ * C_;
  const unsigned short* sb = sa_pk + (size_t)b * C_ * N_;

  v4f acc[4][2];
#pragma unroll
  for (int i = 0; i < 4; ++i)
#pragma unroll
    for (int j = 0; j < 2; ++j) acc[i][j] = (v4f){0.f, 0.f, 0.f, 0.f};

  const int ar16 = (c0 + cw * 64) >> 4;
  const int br16 = (n0 + nw * 32) >> 4;
#pragma unroll 4
  for (int s = 0; s < 16; ++s) {
    v8s b0 = ld8(&sTb[((size_t)(br16 + 0) * 16 + s) * 512 + lanelin]);
    v8s b1 = ld8(&sTb[((size_t)(br16 + 1) * 16 + s) * 512 + lanelin]);
#pragma unroll
    for (int ci = 0; ci < 4; ++ci) {
      v8s a = ld8(&ab[((size_t)(ar16 + ci) * 16 + s) * 512 + lanelin]);
      acc[ci][0] = mfma16(a, b0, acc[ci][0]);
      acc[ci][1] = mfma16(a, b1, acc[ci][1]);
    }
  }
  const float gc = gamma_cam[0];
#pragma unroll
  for (int ci = 0; ci < 4; ++ci)
#pragma unroll
    for (int nj = 0; nj < 2; ++nj)
#pragma unroll
      for (int r = 0; r < 4; ++r) {
        int c = c0 + cw * 64 + ci * 16 + quad * 4 + r;
        int n = n0 + nw * 32 + nj * 16 + la;
        size_t pko = ((size_t)(c >> 4) * 128 + (n >> 5)) * 512 + (c & 15) * 32 + (n & 31);
        out[((size_t)b * C_ + c) * N_ + n] = fmaf(gc, acc[ci][nj][r], bf2f(sb[pko]));
      }
}

// ---------------------------------------------------------------------------
extern "C" void kernel_launch(void* const* d_in, const int* in_sizes, int n_in,
                              void* d_out, int out_size, void* d_ws, size_t ws_size,
                              hipStream_t stream) {
  const float* x  = (const float*)d_in[0];
  const float* wq = (const float*)d_in[1];
  const float* bq = (const float*)d_in[2];
  const float* wk = (const float*)d_in[3];
  const float* bk = (const float*)d_in[4];
  const float* wv = (const float*)d_in[5];
  const float* bv = (const float*)d_in[6];
  const float* gp = (const float*)d_in[7];
  const float* gc = (const float*)d_in[8];
  float* out = (float*)d_out;

  char* ws = (char*)d_ws;
  // Region map (with reuse; total 118.62 MB):
  //  A 0        : x_pk (16.78M)  -> later sa_pk
  //  B 16.78M   : w_pk (1.05M)
  //  C 17.83M   : q_pk (8.39M)   -> later saT_pk (spans C..C+16.78M with k_pk)
  //  D 26.21M   : k_pk (8.39M)
  //  E 34.60M   : v_pk (16.78M)  -> later ep
  //  F 51.38M   : acc_part (67.11M) -> later at_pk (first 2.1M)
  //  G 118.49M  : l_part (128KB)
  unsigned short* x_pk   = (unsigned short*)(ws);
  unsigned short* w_pk   = (unsigned short*)(ws + 16777216);
  unsigned short* q_pk   = (unsigned short*)(ws + 17825792);
  unsigned short* k_pk   = (unsigned short*)(ws + 26214400);
  unsigned short* v_pk   = (unsigned short*)(ws + 34603008);
  float*          acc_p  = (float*)(ws + 51380224);
  float*          l_p    = (float*)(ws + 118489088);
  unsigned short* sa_pk  = (unsigned short*)(ws);              // reuse A
  unsigned short* saT_pk = (unsigned short*)(ws + 17825792);   // reuse C+D
  float*          ep     = (float*)(ws + 34603008);            // reuse E
  unsigned short* at_pk  = (unsigned short*)(ws + 51380224);   // reuse F

  k_xT<<<dim3(64, 8, B_), 256, 0, stream>>>(x, x_pk);
  k_wb<<<256, 256, 0, stream>>>(wq, wk, wv, w_pk);
  k_qkv<<<dim3(32, 8, B_), 512, 0, stream>>>(w_pk, x_pk, bq, bk, bv, q_pk, k_pk, v_pk);
  k_pam<<<512, 512, 0, stream>>>(q_pk, k_pk, v_pk, acc_p, l_p);
  k_combine<<<dim3(64, 8, B_), 256, 0, stream>>>(acc_p, l_p, x, gp, sa_pk, saT_pk);
  k_cam_e<<<dim3(64, 4, B_), 256, 0, stream>>>(sa_pk, ep);
  k_cam_softmax<<<dim3(C_, B_), 64, 0, stream>>>(ep, at_pk);
  k_cam_out<<<dim3(32, 4, B_), 512, 0, stream>>>(at_pk, saT_pk, sa_pk, gc, out);
}

// Round 11
// 360.743 us; speedup vs baseline: 1.2067x; 1.2067x over previous
//
#include <hip/hip_runtime.h>

#define B_ 4
#define C_ 512
#define CI_ 256
#define N_ 4096
#define SCALE_PAM 0.04419417382415922f  // 1/sqrt(512)
#define SCALE_CAM (1.0f/64.0f)          // 1/sqrt(4096)
#define SHIFT_PAM 8.0f

typedef float v4f __attribute__((ext_vector_type(4)));
typedef short v8s __attribute__((ext_vector_type(8)));

__device__ __forceinline__ unsigned short f2bf(float f) {
  unsigned int u = __float_as_uint(f);
  u = (u + 0x7FFFu + ((u >> 16) & 1u)) >> 16;
  return (unsigned short)u;
}
__device__ __forceinline__ float bf2f(unsigned short s) {
  return __uint_as_float(((unsigned int)s) << 16);
}
__device__ __forceinline__ v8s ld8(const unsigned short* p) {
  v8s r; *(int4*)&r = *(const int4*)p; return r;
}
__device__ __forceinline__ v4f mfma16(v8s a, v8s b, v4f c) {
  return __builtin_amdgcn_mfma_f32_16x16x32_bf16(a, b, c, 0, 0, 0);
}
// PK layout: off(r,k) = ((r>>4)*(K>>5) + (k>>5))*512 + (r&15)*32 + (k&31)  [shorts]
// Wave frag load: base + lanelin, lanelin=(lane&15)*32+(lane>>4)*8 -> contiguous 1KB.

// ---------------------------------------------------------------------------
// K_wb: wq/wk/wv fp32 -> w_pk PK(1024,512).
// ---------------------------------------------------------------------------
__global__ __launch_bounds__(256) void k_wb(const float* __restrict__ wq,
                                            const float* __restrict__ wk,
                                            const float* __restrict__ wv,
                                            unsigned short* __restrict__ w_pk) {
  int u = blockIdx.x * 256 + threadIdx.x;
  int blk = u >> 6, wi = (u & 63) * 8;
  int r = (blk >> 4) * 16 + (wi >> 5);
  int k = (blk & 15) * 32 + (wi & 31);
  const float* src = (r < 256) ? &wq[r * 512 + k]
                   : (r < 512) ? &wk[(r - 256) * 512 + k]
                               : &wv[(r - 512) * 512 + k];
  float4 f0 = *(const float4*)src, f1 = *(const float4*)(src + 4);
  ushort4 o0 = { f2bf(f0.x), f2bf(f0.y), f2bf(f0.z), f2bf(f0.w) };
  ushort4 o1 = { f2bf(f1.x), f2bf(f1.y), f2bf(f1.z), f2bf(f1.w) };
  *(ushort4*)&w_pk[u * 8] = o0;
  *(ushort4*)&w_pk[u * 8 + 4] = o1;
}

// ---------------------------------------------------------------------------
// K_xT: x fp32 [b][c][n] -> x_pk PK(4096,512) per batch (rows n, cols c).
// ---------------------------------------------------------------------------
__global__ __launch_bounds__(256) void k_xT(const float* __restrict__ x,
                                            unsigned short* __restrict__ x_pk) {
  const int b = blockIdx.z, c0 = blockIdx.y * 64, n0 = blockIdx.x * 64;
  const int t = threadIdx.x;
  __shared__ unsigned short ts[64 * 72];  // [n][c]
  const int cl = t >> 2, nseg = (t & 3) * 16;
  const float* xr = x + ((size_t)b * C_ + c0 + cl) * N_ + n0 + nseg;
#pragma unroll
  for (int k = 0; k < 4; ++k) {
    float4 f = *(const float4*)(xr + k * 4);
    ts[(nseg + k * 4 + 0) * 72 + cl] = f2bf(f.x);
    ts[(nseg + k * 4 + 1) * 72 + cl] = f2bf(f.y);
    ts[(nseg + k * 4 + 2) * 72 + cl] = f2bf(f.z);
    ts[(nseg + k * 4 + 3) * 72 + cl] = f2bf(f.w);
  }
  __syncthreads();
  unsigned short* dst = x_pk + (size_t)b * N_ * C_;
#pragma unroll
  for (int u = t; u < 512; u += 256) {
    int blk = u >> 6, wi = (u & 63) * 8;
    int rl = (blk >> 1) * 16 + (wi >> 5);
    int kl = (blk & 1) * 32 + (wi & 31);
    int gr = n0 + rl, gk = c0 + kl;
    size_t go = ((size_t)(gr >> 4) * 16 + (gk >> 5)) * 512 + (gr & 15) * 32 + (gk & 31);
    *(int4*)&dst[go] = *(int4*)&ts[rl * 72 + kl];
  }
}

// ---------------------------------------------------------------------------
// K_qkv: y[o][n] = sum_c W[o][c] x[n][c] + b.  128o x 128n tile, 512 thr.
// ---------------------------------------------------------------------------
__global__ __launch_bounds__(512) void k_qkv(
    const unsigned short* __restrict__ w_pk, const unsigned short* __restrict__ x_pk,
    const float* __restrict__ bq, const float* __restrict__ bk, const float* __restrict__ bv,
    unsigned short* __restrict__ q_pk, unsigned short* __restrict__ k_pk,
    unsigned short* __restrict__ v_pk) {
  const int b = blockIdx.z, o0 = blockIdx.y * 128, n0 = blockIdx.x * 128;
  const int t = threadIdx.x, wave = t >> 6, lane = t & 63;
  const int la = lane & 15, quad = lane >> 4;
  const int ow = wave & 1, nw = wave >> 1;
  const int lanelin = la * 32 + quad * 8;
  const unsigned short* xpb = x_pk + (size_t)b * N_ * C_;
  __shared__ unsigned short tp[128 * 136];

  v4f acc[4][2];
#pragma unroll
  for (int i = 0; i < 4; ++i)
#pragma unroll
    for (int j = 0; j < 2; ++j) acc[i][j] = (v4f){0.f, 0.f, 0.f, 0.f};

  const int ar16 = (o0 + ow * 64) >> 4;
  const int br16 = (n0 + nw * 32) >> 4;
#pragma unroll 4
  for (int s = 0; s < 16; ++s) {
    v8s b0 = ld8(&xpb[((size_t)(br16 + 0) * 16 + s) * 512 + lanelin]);
    v8s b1 = ld8(&xpb[((size_t)(br16 + 1) * 16 + s) * 512 + lanelin]);
#pragma unroll
    for (int oi = 0; oi < 4; ++oi) {
      v8s a = ld8(&w_pk[((size_t)(ar16 + oi) * 16 + s) * 512 + lanelin]);
      acc[oi][0] = mfma16(a, b0, acc[oi][0]);
      acc[oi][1] = mfma16(a, b1, acc[oi][1]);
    }
  }

  if (o0 >= 512) {
#pragma unroll
    for (int oi = 0; oi < 4; ++oi)
#pragma unroll
      for (int nj = 0; nj < 2; ++nj)
#pragma unroll
        for (int r = 0; r < 4; ++r) {
          int cl = ow * 64 + oi * 16 + quad * 4 + r;
          int nl = nw * 32 + nj * 16 + la;
          tp[cl * 136 + nl] = f2bf(acc[oi][nj][r] + bv[o0 - 512 + cl]);
        }
    __syncthreads();
    unsigned short* dst = v_pk + (size_t)b * C_ * N_;
#pragma unroll
    for (int u = t; u < 2048; u += 512) {
      int blk = u >> 6, wi = (u & 63) * 8;
      int rl = (blk >> 2) * 16 + (wi >> 5);
      int kl = (blk & 3) * 32 + (wi & 31);
      int gr = (o0 - 512) + rl, gk = n0 + kl;
      size_t go = ((size_t)(gr >> 4) * 128 + (gk >> 5)) * 512 + (gr & 15) * 32 + (gk & 31);
      *(int4*)&dst[go] = *(int4*)&tp[rl * 136 + kl];
    }
  } else {
    const float* bias = (o0 < 256) ? bq : bk;
#pragma unroll
    for (int oi = 0; oi < 4; ++oi)
#pragma unroll
      for (int nj = 0; nj < 2; ++nj)
#pragma unroll
        for (int r = 0; r < 4; ++r) {
          int ol = ow * 64 + oi * 16 + quad * 4 + r;
          int nl = nw * 32 + nj * 16 + la;
          tp[nl * 136 + ol] = f2bf(acc[oi][nj][r] + bias[(o0 & 255) + ol]);
        }
    __syncthreads();
    unsigned short* dst = ((o0 < 256) ? q_pk : k_pk) + (size_t)b * N_ * CI_;
#pragma unroll
    for (int u = t; u < 2048; u += 512) {
      int blk = u >> 6, wi = (u & 63) * 8;
      int rl = (blk >> 2) * 16 + (wi >> 5);
      int kl = (blk & 3) * 32 + (wi & 31);
      int gr = n0 + rl, gk = (o0 & 255) + kl;
      size_t go = ((size_t)(gr >> 4) * 8 + (gk >> 5)) * 512 + (gr & 15) * 32 + (gk & 31);
      *(int4*)&dst[go] = *(int4*)&tp[rl * 136 + kl];
    }
  }
}

// ---------------------------------------------------------------------------
// K_pam v15: v8's core loop VERBATIM (166us, 1024 thr, K tbuf DMA, counted
// vmcnt(6)) extended to the FULL j range (64 steps, no jh split; grid 256 =
// 1 block/CU), with k_combine FUSED as an epilogue: block ends holding
// complete acc + l, computes sa = tanh(gp*acc/(l*N) + x) in-register and
// emits sa_pk + saT_pk via LDS-staged PK writes (reusing kls' 96KB).
// Removes k_combine kernel + 134MB of acc_part HBM round-trip.
// b = blk&3 -> one batch per XCD (round-robin dispatch): K 2MB + streamed V
// per XCD L2. sa/saT land in the (dead) acc_part region — NOT over q/k,
// which co-resident blocks still read.
// ---------------------------------------------------------------------------
__device__ __forceinline__ void kstage(const unsigned short* g, unsigned short* l, int t) {
  // 1024 threads stage a contiguous 32KB K tile: 2 x 16B per thread.
  __builtin_amdgcn_global_load_lds(
      (const __attribute__((address_space(1))) void*)(g + (size_t)t * 8),
      (__attribute__((address_space(3))) void*)(l + t * 8), 16, 0, 0);
  __builtin_amdgcn_global_load_lds(
      (const __attribute__((address_space(1))) void*)(g + 8192 + (size_t)t * 8),
      (__attribute__((address_space(3))) void*)(l + 8192 + t * 8), 16, 0, 0);
}

__global__ __launch_bounds__(1024) void k_pam(
    const unsigned short* __restrict__ q_pk, const unsigned short* __restrict__ k_pk,
    const unsigned short* __restrict__ v_pk, const float* __restrict__ x,
    const float* __restrict__ gamma_pam,
    unsigned short* __restrict__ sa_pk, unsigned short* __restrict__ saT_pk) {
  const int blk = blockIdx.x;
  const int b = blk & 3, i0 = (blk >> 2) * 64;
  const int t = threadIdx.x, wave = t >> 6, lane = t & 63;
  const int la = lane & 15, quad = lane >> 4;
  const int iw = wave & 3, jw = wave >> 2;
  const int cb = wave * 32;
  const int lanelin = la * 32 + quad * 8;

  __shared__ unsigned short kls[3][16384];  // 3 x 32KB K tiles; reused by epilogue
  __shared__ unsigned short pa[2][4096];    // 64x64 P, XOR-swizzled stride 64
  __shared__ float l_lds[64];
  if (t < 64) l_lds[t] = 0.f;

  const unsigned short* qpk = q_pk + (size_t)b * N_ * CI_;
  const unsigned short* kpk = k_pk + (size_t)b * N_ * CI_;
  const unsigned short* vpk = v_pk + (size_t)b * C_ * N_;

  v8s qf[8];
  {
    const unsigned short* qb = qpk + ((size_t)((i0 >> 4) + iw) * 8) * 512 + lanelin;
#pragma unroll
    for (int s = 0; s < 8; ++s) qf[s] = ld8(qb + s * 512);
  }

  v4f acc[2][4];  // [ct][it]
#pragma unroll
  for (int ct = 0; ct < 2; ++ct)
#pragma unroll
    for (int it = 0; it < 4; ++it) acc[ct][it] = (v4f){0.f, 0.f, 0.f, 0.f};
  float lsum[4] = {0.f, 0.f, 0.f, 0.f};

  // prologue: stage step0 -> kls[0], step1 -> kls[1]; drain step0 only.
  kstage(kpk, kls[0], t);
  kstage(kpk + (size_t)4 * 4096, kls[1], t);
  asm volatile("s_waitcnt vmcnt(2)" ::: "memory");  // DMA_0 done (in-order drain)
  __builtin_amdgcn_s_barrier();
  __builtin_amdgcn_sched_barrier(0);

  int pb = 0;
  for (int step = 0; step < 64; ++step) {
    const int j0 = step * 64;
    // phase 1: V frags (issued FIRST so PV waits vmcnt(2), not 0)
    v8s vf[2][2];
#pragma unroll
    for (int ct = 0; ct < 2; ++ct)
#pragma unroll
      for (int ks = 0; ks < 2; ++ks)
        vf[ct][ks] = ld8(&vpk[((size_t)((cb >> 4) + ct) * 128 + (j0 >> 5) + ks) * 512 + lanelin]);
    __builtin_amdgcn_sched_barrier(0);
    // phase 2: DMA K tile for step+2 into kls[(step+2)%3]
    int jn = j0 + 128; if (jn >= N_) jn = 0;  // tail clamp (data unused)
    kstage(kpk + (size_t)(jn >> 4) * 4096, kls[(step + 2) % 3], t);
    __builtin_amdgcn_sched_barrier(0);
    // phase 3: S = Q K^T from kls[step%3] (staged 2 steps ago; guaranteed by
    // previous step's vmcnt(6)+s_barrier)
    const unsigned short* kb = &kls[step % 3][jw * 4096 + lanelin];
    v4f sA = (v4f){0.f, 0.f, 0.f, 0.f}, sB = sA;
#pragma unroll
    for (int sh = 0; sh < 4; ++sh) {
      sA = mfma16(qf[sh], ld8(kb + sh * 512), sA);
      sB = mfma16(qf[sh + 4], ld8(kb + (sh + 4) * 512), sB);
    }
    // phase 4: P = exp(s*scale - shift), swizzled LDS write
#pragma unroll
    for (int r = 0; r < 4; ++r) {
      float p = __expf((sA[r] + sB[r]) * SCALE_PAM - SHIFT_PAM);
      lsum[r] += p;
      int row = iw * 16 + quad * 4 + r;
      pa[pb][((row << 6) + jw * 16 + la) ^ ((row & 7) << 3)] = f2bf(p);
    }
    // phase 5: fence. lgkmcnt(0): our P writes visible. vmcnt(6): drains the
    // 2 oldest vmem = DMA for step+1 (queue: DMA_{t+1}(2), V_t(4), DMA_{t+2}(2)).
    __builtin_amdgcn_sched_barrier(0);
    asm volatile("s_waitcnt lgkmcnt(0) vmcnt(6)" ::: "memory");
    __builtin_amdgcn_s_barrier();
    __builtin_amdgcn_sched_barrier(0);
    // phase 6: PV: acc[c][i] += V[c][j] * P[i][j]  (compiler waits vmcnt(2) for vf)
    __builtin_amdgcn_s_setprio(1);
#pragma unroll
    for (int it = 0; it < 4; ++it) {
      const int row = it * 16 + la;
      const int sw = (row & 7) << 3;
#pragma unroll
      for (int ks = 0; ks < 2; ++ks) {
        v8s pf; *(int4*)&pf = *(const int4*)&pa[pb][((row << 6) + ks * 32 + quad * 8) ^ sw];
#pragma unroll
        for (int ct = 0; ct < 2; ++ct)
          acc[ct][it] = mfma16(vf[ct][ks], pf, acc[ct][it]);
      }
    }
    __builtin_amdgcn_s_setprio(0);
    pb ^= 1;
  }

  // ---- fused k_combine epilogue ----
  // l reduction: la-lanes within quad, then 4 jw waves via LDS atomic
#pragma unroll
  for (int r = 0; r < 4; ++r) {
    float v = lsum[r];
    v += __shfl_xor(v, 1); v += __shfl_xor(v, 2);
    v += __shfl_xor(v, 4); v += __shfl_xor(v, 8);
    if (la == 0) atomicAdd(&l_lds[iw * 16 + quad * 4 + r], v);
  }
  __syncthreads();  // l complete; all waves past PV (kls free to reuse)

  const float gpv = gamma_pam[0];
  unsigned short* ts = &kls[0][0];  // stage 1: ts[c][72] (512*72 shorts = 73.7KB)
  unsigned short sv[2][4][4];
#pragma unroll
  for (int ct = 0; ct < 2; ++ct)
#pragma unroll
    for (int it = 0; it < 4; ++it) {
      const int nl = it * 16 + la;
      const float lv = l_lds[nl] * (float)N_;
#pragma unroll
      for (int r = 0; r < 4; ++r) {
        const int c = cb + ct * 16 + quad * 4 + r;
        const float xv = x[((size_t)b * C_ + c) * N_ + i0 + nl];
        const unsigned short h = f2bf(tanhf(fmaf(gpv, acc[ct][it][r] / lv, xv)));
        sv[ct][it][r] = h;
        ts[c * 72 + nl] = h;
      }
    }
  __syncthreads();
  {  // sa_pk: PK(512 c, 4096 n), row-block stride 128
    unsigned short* dst = sa_pk + (size_t)b * C_ * N_;
#pragma unroll
    for (int u = t; u < 4096; u += 1024) {
      int c = u >> 3, n8 = (u & 7) * 8;
      int gn = i0 + n8;
      size_t go = ((size_t)(c >> 4) * 128 + (gn >> 5)) * 512 + (c & 15) * 32 + (gn & 31);
      *(int4*)&dst[go] = *(const int4*)&ts[c * 72 + n8];
    }
  }
  __syncthreads();
  unsigned short* ts2 = &kls[0][0];  // stage 2: ts2[n][520] (64*520 = 66.6KB)
#pragma unroll
  for (int ct = 0; ct < 2; ++ct)
#pragma unroll
    for (int it = 0; it < 4; ++it)
#pragma unroll
      for (int r = 0; r < 4; ++r)
        ts2[(it * 16 + la) * 520 + (cb + ct * 16 + quad * 4 + r)] = sv[ct][it][r];
  __syncthreads();
  {  // saT_pk: PK(4096 n, 512 c), row-block stride 16
    unsigned short* dst = saT_pk + (size_t)b * N_ * C_;
#pragma unroll
    for (int u = t; u < 4096; u += 1024) {
      int nl = u >> 6, c8 = (u & 63) * 8;
      int gn = i0 + nl;
      size_t go = ((size_t)(gn >> 4) * 16 + (c8 >> 5)) * 512 + (gn & 15) * 32 + (c8 & 31);
      *(int4*)&dst[go] = *(const int4*)&ts2[nl * 520 + c8];
    }
  }
}

// ---------------------------------------------------------------------------
// K_cam_e: e_part[ks][b][c][d] = scale * sum_n sa_c sa_d.  64x64 tile, ks4.
// ---------------------------------------------------------------------------
__global__ __launch_bounds__(256) void k_cam_e(const unsigned short* __restrict__ sa_pk,
                                               float* __restrict__ e_part) {
  const int b = blockIdx.z, ks = blockIdx.y;
  const int c0 = (blockIdx.x & 7) * 64, d0 = (blockIdx.x >> 3) * 64;
  const int t = threadIdx.x, wave = t >> 6, lane = t & 63;
  const int la = lane & 15, quad = lane >> 4;
  const int cw = wave & 1, dw = wave >> 1;
  const int lanelin = la * 32 + quad * 8;
  const unsigned short* sb = sa_pk + (size_t)b * C_ * N_;

  v4f acc[2][2];
#pragma unroll
  for (int i = 0; i < 2; ++i)
#pragma unroll
    for (int j = 0; j < 2; ++j) acc[i][j] = (v4f){0.f, 0.f, 0.f, 0.f};

  const int ar16 = (c0 + cw * 32) >> 4;
  const int br16 = (d0 + dw * 32) >> 4;
#pragma unroll 4
  for (int s = 0; s < 32; ++s) {
    const int k32 = ks * 32 + s;
    v8s a0 = ld8(&sb[((size_t)(ar16 + 0) * 128 + k32) * 512 + lanelin]);
    v8s a1 = ld8(&sb[((size_t)(ar16 + 1) * 128 + k32) * 512 + lanelin]);
    v8s b0 = ld8(&sb[((size_t)(br16 + 0) * 128 + k32) * 512 + lanelin]);
    v8s b1 = ld8(&sb[((size_t)(br16 + 1) * 128 + k32) * 512 + lanelin]);
    acc[0][0] = mfma16(a0, b0, acc[0][0]);
    acc[0][1] = mfma16(a0, b1, acc[0][1]);
    acc[1][0] = mfma16(a1, b0, acc[1][0]);
    acc[1][1] = mfma16(a1, b1, acc[1][1]);
  }
  float* ep = e_part + ((size_t)(ks * B_ + b)) * C_ * C_;
#pragma unroll
  for (int i = 0; i < 2; ++i)
#pragma unroll
    for (int j = 0; j < 2; ++j)
#pragma unroll
      for (int r = 0; r < 4; ++r) {
        int c = c0 + cw * 32 + i * 16 + quad * 4 + r;
        int d = d0 + dw * 32 + j * 16 + la;
        ep[(size_t)c * C_ + d] = acc[i][j][r] * SCALE_CAM;
      }
}

// ---------------------------------------------------------------------------
// K_cam_softmax: min-trick softmax over 4 parts -> attn_pk PK(512,512).
// ---------------------------------------------------------------------------
__global__ __launch_bounds__(64) void k_cam_softmax(const float* __restrict__ e_part,
                                                    unsigned short* __restrict__ attn_pk) {
  const int c = blockIdx.x, b = blockIdx.y, lane = threadIdx.x;
  size_t roff = ((size_t)b * C_ + c) * C_;
  float vals[8];
#pragma unroll
  for (int r = 0; r < 8; ++r) {
    int d = lane + r * 64;
    float s = 0.f;
#pragma unroll
    for (int p = 0; p < 4; ++p) s += e_part[(size_t)(p * B_) * C_ * C_ + roff + d];
    vals[r] = s;
  }
  float mn = vals[0];
#pragma unroll
  for (int r = 1; r < 8; ++r) mn = fminf(mn, vals[r]);
#pragma unroll
  for (int m = 32; m >= 1; m >>= 1) mn = fminf(mn, __shfl_xor(mn, m));
  float sum = 0.f;
#pragma unroll
  for (int r = 0; r < 8; ++r) { vals[r] = __expf(mn - vals[r]); sum += vals[r]; }
#pragma unroll
  for (int m = 32; m >= 1; m >>= 1) sum += __shfl_xor(sum, m);
  float sc = (1.0f / (float)C_) / sum;
  unsigned short* ab = attn_pk + (size_t)b * C_ * C_;
#pragma unroll
  for (int r = 0; r < 8; ++r) {
    int d = lane + r * 64;
    size_t go = ((size_t)(c >> 4) * 16 + (d >> 5)) * 512 + (c & 15) * 32 + (d & 31);
    ab[go] = f2bf(vals[r] * sc);
  }
}

// ---------------------------------------------------------------------------
// K_cam_out: out = gc * (attn @ sa) + sa.  128c x 128n tile, 512 thr.
// ---------------------------------------------------------------------------
__global__ __launch_bounds__(512) void k_cam_out(
    const unsigned short* __restrict__ attn_pk, const unsigned short* __restrict__ saT_pk,
    const unsigned short* __restrict__ sa_pk, const float* __restrict__ gamma_cam,
    float* __restrict__ out) {
  const int b = blockIdx.z, c0 = blockIdx.y * 128, n0 = blockIdx.x * 128;
  const int t = threadIdx.x, wave = t >> 6, lane = t & 63;
  const int la = lane & 15, quad = lane >> 4;
  const int cw = wave & 1, nw = wave >> 1;
  const int lanelin = la * 32 + quad * 8;
  const unsigned short* ab = attn_pk + (size_t)b * C_ * C_;
  const unsigned short* sTb = saT_pk + (size_t)b * N_ * C_;
  const unsigned short* sb = sa_pk + (size_t)b * C_ * N_;

  v4f acc[4][2];
#pragma unroll
  for (int i = 0; i < 4; ++i)
#pragma unroll
    for (int j = 0; j < 2; ++j) acc[i][j] = (v4f){0.f, 0.f, 0.f, 0.f};

  const int ar16 = (c0 + cw * 64) >> 4;
  const int br16 = (n0 + nw * 32) >> 4;
#pragma unroll 4
  for (int s = 0; s < 16; ++s) {
    v8s b0 = ld8(&sTb[((size_t)(br16 + 0) * 16 + s) * 512 + lanelin]);
    v8s b1 = ld8(&sTb[((size_t)(br16 + 1) * 16 + s) * 512 + lanelin]);
#pragma unroll
    for (int ci = 0; ci < 4; ++ci) {
      v8s a = ld8(&ab[((size_t)(ar16 + ci) * 16 + s) * 512 + lanelin]);
      acc[ci][0] = mfma16(a, b0, acc[ci][0]);
      acc[ci][1] = mfma16(a, b1, acc[ci][1]);
    }
  }
  const float gc = gamma_cam[0];
#pragma unroll
  for (int ci = 0; ci < 4; ++ci)
#pragma unroll
    for (int nj = 0; nj < 2; ++nj)
#pragma unroll
      for (int r = 0; r < 4; ++r) {
        int c = c0 + cw * 64 + ci * 16 + quad * 4 + r;
        int n = n0 + nw * 32 + nj * 16 + la;
        size_t pko = ((size_t)(c >> 4) * 128 + (n >> 5)) * 512 + (c & 15) * 32 + (n & 31);
        out[((size_t)b * C_ + c) * N_ + n] = fmaf(gc, acc[ci][nj][r], bf2f(sb[pko]));
      }
}

// ---------------------------------------------------------------------------
extern "C" void kernel_launch(void* const* d_in, const int* in_sizes, int n_in,
                              void* d_out, int out_size, void* d_ws, size_t ws_size,
                              hipStream_t stream) {
  const float* x  = (const float*)d_in[0];
  const float* wq = (const float*)d_in[1];
  const float* bq = (const float*)d_in[2];
  const float* wk = (const float*)d_in[3];
  const float* bk = (const float*)d_in[4];
  const float* wv = (const float*)d_in[5];
  const float* bv = (const float*)d_in[6];
  const float* gp = (const float*)d_in[7];
  const float* gc = (const float*)d_in[8];
  float* out = (float*)d_out;

  char* ws = (char*)d_ws;
  // Region map (k_combine fused into k_pam; max used = 84.9 MB):
  //  A 0        : x_pk (16.78M)   -> later at_pk (2.1M)
  //  B 16.78M   : w_pk (1.05M)
  //  C 17.83M   : q_pk (8.39M)    (live through k_pam)
  //  D 26.21M   : k_pk (8.39M)    (live through k_pam)
  //  E 34.60M   : v_pk (16.78M)   -> later ep (16.78M)
  //  F 51.38M   : sa_pk (16.78M)
  //  G 68.16M   : saT_pk (16.78M)
  unsigned short* x_pk   = (unsigned short*)(ws);
  unsigned short* w_pk   = (unsigned short*)(ws + 16777216);
  unsigned short* q_pk   = (unsigned short*)(ws + 17825792);
  unsigned short* k_pk   = (unsigned short*)(ws + 26214400);
  unsigned short* v_pk   = (unsigned short*)(ws + 34603008);
  unsigned short* sa_pk  = (unsigned short*)(ws + 51380224);
  unsigned short* saT_pk = (unsigned short*)(ws + 68157440);
  float*          ep     = (float*)(ws + 34603008);            // reuse E
  unsigned short* at_pk  = (unsigned short*)(ws);              // reuse A

  k_xT<<<dim3(64, 8, B_), 256, 0, stream>>>(x, x_pk);
  k_wb<<<256, 256, 0, stream>>>(wq, wk, wv, w_pk);
  k_qkv<<<dim3(32, 8, B_), 512, 0, stream>>>(w_pk, x_pk, bq, bk, bv, q_pk, k_pk, v_pk);
  k_pam<<<256, 1024, 0, stream>>>(q_pk, k_pk, v_pk, x, gp, sa_pk, saT_pk);
  k_cam_e<<<dim3(64, 4, B_), 256, 0, stream>>>(sa_pk, ep);
  k_cam_softmax<<<dim3(C_, B_), 64, 0, stream>>>(ep, at_pk);
  k_cam_out<<<dim3(32, 4, B_), 512, 0, stream>>>(at_pk, saT_pk, sa_pk, gc, out);
}